// Round 7
// baseline (891.235 us; speedup 1.0000x reference)
//
#include <hip/hip_runtime.h>
#include <hip/hip_bf16.h>

#define NN 50000
#define EE 250000
#define HH 128
#define EPS_ 1e-5f
#define SCB 196  // scan segments per relation: ceil(NN/256)

typedef __attribute__((ext_vector_type(8))) short bf16x8;
typedef __attribute__((ext_vector_type(4))) float f32x4;

__device__ __forceinline__ float bf2f(ushort u) {
  union { unsigned int i; float f; } x; x.i = ((unsigned int)u) << 16; return x.f;
}
__device__ __forceinline__ ushort f2bf(float f) {
  union { float f; unsigned int i; } x; x.f = f;
  unsigned int r = (x.i + 0x7fffu + ((x.i >> 16) & 1u)) >> 16;  // RNE, finite inputs
  return (ushort)r;
}

// ---------------- degree / CSR build ----------------
__global__ void k_count(const int* __restrict__ bei, const int* __restrict__ cei,
                        int* __restrict__ cntb, int* __restrict__ cntc) {
  int i = blockIdx.x * blockDim.x + threadIdx.x;
  if (i < EE) atomicAdd(&cntb[bei[EE + i]], 1);
  else if (i < 2 * EE) atomicAdd(&cntc[cei[EE + (i - EE)]], 1);
}

__global__ void k_dinv(const int* __restrict__ cnt, float* __restrict__ dinv) {
  int i = blockIdx.x * blockDim.x + threadIdx.x;  // 2N: [cntb|cntc] -> [dinvb|dinvc]
  if (i < 2 * NN) dinv[i] = rsqrtf((float)cnt[i] + 1.0f);
}

// ---- parallel 2-level exclusive scan over cnt[2N] -> off[2N], cur[2N] ----
__global__ void k_scan_part(const int* __restrict__ cnt, int* __restrict__ part) {
  int rel = blockIdx.x / SCB, b = blockIdx.x % SCB;
  int n = b * 256 + threadIdx.x;
  int v = (n < NN) ? cnt[rel * NN + n] : 0;
#pragma unroll
  for (int m = 32; m >= 1; m >>= 1) v += __shfl_xor(v, m, 64);
  __shared__ int red[4];
  if ((threadIdx.x & 63) == 0) red[threadIdx.x >> 6] = v;
  __syncthreads();
  if (threadIdx.x == 0) part[rel * SCB + b] = red[0] + red[1] + red[2] + red[3];
}

__global__ void k_scan_base(int* __restrict__ part) {
  __shared__ int s[256];
  int t = threadIdx.x;
  for (int rel = 0; rel < 2; ++rel) {
    int v = (t < SCB) ? part[rel * SCB + t] : 0;
    s[t] = v;
    __syncthreads();
    for (int ofs = 1; ofs < 256; ofs <<= 1) {
      int x = (t >= ofs) ? s[t - ofs] : 0;
      __syncthreads();
      s[t] += x;
      __syncthreads();
    }
    if (t < SCB) part[rel * SCB + t] = s[t] - v;  // exclusive
    __syncthreads();
  }
}

__global__ void k_scan_off(const int* __restrict__ cnt, const int* __restrict__ part,
                           int* __restrict__ off, int* __restrict__ cur) {
  int rel = blockIdx.x / SCB, b = blockIdx.x % SCB;
  int t = threadIdx.x;
  int n = b * 256 + t;
  int v = (n < NN) ? cnt[rel * NN + n] : 0;
  __shared__ int s[256];
  s[t] = v;
  __syncthreads();
  for (int ofs = 1; ofs < 256; ofs <<= 1) {
    int x = (t >= ofs) ? s[t - ofs] : 0;
    __syncthreads();
    s[t] += x;
    __syncthreads();
  }
  if (n < NN) {
    int o = part[rel * SCB + b] + s[t] - v;
    off[rel * NN + n] = o;
    cur[rel * NN + n] = o;
  }
}

__global__ void k_fill(const int* __restrict__ bei, const int* __restrict__ cei,
                       int* __restrict__ curb, int* __restrict__ listb,
                       int* __restrict__ curc, int* __restrict__ listc) {
  int i = blockIdx.x * blockDim.x + threadIdx.x;
  if (i < EE) {
    int dst = bei[EE + i];
    int p = atomicAdd(&curb[dst], 1);
    listb[p] = bei[i];
  } else if (i < 2 * EE) {
    int e = i - EE;
    int dst = cei[EE + e];
    int p = atomicAdd(&curc[dst], 1);
    listc[p] = cei[e];
  }
}

// ---------------- encoder: relu(x@W_enc+b) -> bf16, accumulate BN stats ----------------
__global__ void k_encoder_bf(const float* __restrict__ x, const float* __restrict__ W,
                             const float* __restrict__ b, ushort* __restrict__ hb,
                             float* __restrict__ sum, float* __restrict__ sumsq) {
  int t = threadIdx.x;
  int c = t & 127, r = t >> 7;
  int n0 = blockIdx.x * 64;
  float w0 = W[c], w1 = W[HH + c], w2 = W[2 * HH + c], bb = b[c];
  float ls = 0.f, lss = 0.f;
  for (int rr = r; rr < 64; rr += 2) {
    int n = n0 + rr;
    if (n < NN) {
      float v = fmaxf(x[n * 3] * w0 + x[n * 3 + 1] * w1 + x[n * 3 + 2] * w2 + bb, 0.f);
      ushort u = f2bf(v);
      hb[(size_t)n * HH + c] = u;
      float vr = bf2f(u);          // stats on the rounded value (self-consistent BN)
      ls += vr; lss += vr * vr;
    }
  }
  __shared__ float red[2][HH];
  red[r][c] = ls; __syncthreads();
  if (r == 0) atomicAdd(&sum[c], red[0][c] + red[1][c]);
  __syncthreads();
  red[r][c] = lss; __syncthreads();
  if (r == 0) atomicAdd(&sumsq[c], red[0][c] + red[1][c]);
}

__global__ void k_bn_finalize(const float* __restrict__ sum, const float* __restrict__ sumsq,
                              const float* __restrict__ g, const float* __restrict__ be,
                              float* __restrict__ scale, float* __restrict__ shift, float invn) {
  int c = threadIdx.x;
  float m = sum[c] * invn;
  float v = fmaxf(sumsq[c] * invn - m * m, 0.f);
  float s = g[c] * rsqrtf(v + EPS_);
  scale[c] = s;
  shift[c] = be[c] - m * s;
}

// merged 2-relation finalize; st layout: [sum0,sq0,sum1,sq1,scale0,shift0,scale1,shift1]
__global__ void k_bn_finalize2(float* __restrict__ st, const float* __restrict__ g0,
                               const float* __restrict__ be0, const float* __restrict__ g1,
                               const float* __restrict__ be1, float invn) {
  int t = threadIdx.x;  // 256
  int rel = t >> 7, c = t & 127;
  const float* sum = st + rel * 2 * HH;
  const float* sq  = sum + HH;
  float* scale = st + 4 * HH + rel * 2 * HH;
  float* shift = scale + HH;
  const float* g = rel ? g1 : g0;
  const float* be = rel ? be1 : be0;
  float m = sum[c] * invn;
  float v = fmaxf(sq[c] * invn - m * m, 0.f);
  float s = g[c] * rsqrtf(v + EPS_);
  scale[c] = s;
  shift[c] = be[c] - m * s;
}

__global__ void k_bn_apply_bf(ushort* __restrict__ hb, const float* __restrict__ scale,
                              const float* __restrict__ shift) {
  int i = blockIdx.x * 256 + threadIdx.x;  // i over N*H/4
  if (i * 4 < NN * HH) {
    int base = i * 4, c0 = base & 127;
    ushort4 u = *(ushort4*)&hb[base];
    u.x = f2bf(bf2f(u.x) * scale[c0] + shift[c0]);
    u.y = f2bf(bf2f(u.y) * scale[c0 + 1] + shift[c0 + 1]);
    u.z = f2bf(bf2f(u.z) * scale[c0 + 2] + shift[c0 + 2]);
    u.w = f2bf(bf2f(u.w) * scale[c0 + 3] + shift[c0 + 3]);
    *(ushort4*)&hb[base] = u;
  }
}

// ---------------- weight transposes to bf16 ----------------
__global__ void k_wt128_all(const float* __restrict__ s0, const float* __restrict__ s1,
                            const float* __restrict__ s2, const float* __restrict__ s3,
                            ushort* __restrict__ d0, ushort* __restrict__ d1,
                            ushort* __restrict__ d2, ushort* __restrict__ d3) {
  int i = blockIdx.x * 256 + threadIdx.x;
  if (i < 4 * 128 * 128) {
    int sel = i >> 14, loc = i & 16383;
    int k = loc >> 7, c = loc & 127;
    const float* s = sel == 0 ? s0 : sel == 1 ? s1 : sel == 2 ? s2 : s3;
    ushort* d = sel == 0 ? d0 : sel == 1 ? d1 : sel == 2 ? d2 : d3;
    d[c * 128 + k] = f2bf(s[loc]);
  }
}

__global__ void k_wt256_all(const float* __restrict__ s0, const float* __restrict__ s1,
                            ushort* __restrict__ d0, ushort* __restrict__ d1) {
  int i = blockIdx.x * 256 + threadIdx.x;
  if (i < 2 * 256 * 128) {
    int sel = i >> 15, loc = i & 32767;
    int k = loc >> 7, c = loc & 127;
    const float* s = sel ? s1 : s0;
    ushort* d = sel ? d1 : d0;
    d[c * 256 + k] = f2bf(s[loc]);
  }
}

// ---------------- bf16 GEMM pair: Y{0,1}[N,128] = X[N,128] @ W{0,1} ----------------
__global__ __launch_bounds__(256) void k_gemm_bf2(const ushort* __restrict__ X,
                                                  const ushort* __restrict__ Wt0,
                                                  ushort* __restrict__ Y0,
                                                  const ushort* __restrict__ Wt1,
                                                  ushort* __restrict__ Y1) {
  const int nb = gridDim.x >> 1;
  const int rel = blockIdx.x >= nb;
  const int blk = rel ? blockIdx.x - nb : blockIdx.x;
  const ushort* Wt = rel ? Wt1 : Wt0;
  ushort* Y = rel ? Y1 : Y0;
  const int t = threadIdx.x;
  const int l = t & 63, wid = t >> 6;
  const int wm = wid >> 1, wn = wid & 1;
  const int lr = l & 15, lg = l >> 4;
  const int n0 = blk * 64;
  f32x4 acc[2][4];
#pragma unroll
  for (int mf = 0; mf < 2; ++mf)
#pragma unroll
    for (int nf = 0; nf < 4; ++nf) acc[mf][nf] = (f32x4){0.f, 0.f, 0.f, 0.f};
  int r0 = n0 + wm * 32 + lr;
  int rA = min(r0, NN - 1), rB = min(r0 + 16, NN - 1);
  const ushort* xa = X + (size_t)rA * HH + lg * 8;
  const ushort* xb = X + (size_t)rB * HH + lg * 8;
#pragma unroll
  for (int ks = 0; ks < 4; ++ks) {
    bf16x8 a0 = *(const bf16x8*)(xa + ks * 32);
    bf16x8 a1 = *(const bf16x8*)(xb + ks * 32);
#pragma unroll
    for (int nf = 0; nf < 4; ++nf) {
      int col = wn * 64 + nf * 16 + lr;
      bf16x8 b = *(const bf16x8*)(Wt + col * 128 + ks * 32 + lg * 8);
      acc[0][nf] = __builtin_amdgcn_mfma_f32_16x16x32_bf16(a0, b, acc[0][nf], 0, 0, 0);
      acc[1][nf] = __builtin_amdgcn_mfma_f32_16x16x32_bf16(a1, b, acc[1][nf], 0, 0, 0);
    }
  }
#pragma unroll
  for (int mf = 0; mf < 2; ++mf)
#pragma unroll
    for (int nf = 0; nf < 4; ++nf) {
      int col = wn * 64 + nf * 16 + lr;
#pragma unroll
      for (int j = 0; j < 4; ++j) {
        int row = n0 + wm * 32 + mf * 16 + lg * 4 + j;
        if (row < NN) Y[(size_t)row * HH + col] = f2bf(acc[mf][nf][j]);
      }
    }
}

// ---------------- fused aggregation: bias+self+both relations (+relu) -> bf16 ----------------
template <int RELU>
__global__ void k_agg(const ushort* __restrict__ xwb, const ushort* __restrict__ xwc,
                      const float* __restrict__ dinvb, const float* __restrict__ dinvc,
                      const int* __restrict__ offb, const int* __restrict__ cntb,
                      const int* __restrict__ listb,
                      const int* __restrict__ offc, const int* __restrict__ cntc,
                      const int* __restrict__ listc,
                      const float* __restrict__ bb, const float* __restrict__ bc,
                      ushort* __restrict__ out) {
  int t = threadIdx.x;
  int n = blockIdx.x * 2 + (t >> 7);
  int c = t & 127;
  if (n >= NN) return;
  float dnb = dinvb[n], dnc = dinvc[n];
  float acc = bb[c] + bc[c] + dnb * dnb * bf2f(xwb[(size_t)n * HH + c])
                            + dnc * dnc * bf2f(xwc[(size_t)n * HH + c]);
  int o = offb[n], e = o + cntb[n];
  float s = 0.f;
  for (; o < e; ++o) { int src = listb[o]; s += dinvb[src] * bf2f(xwb[(size_t)src * HH + c]); }
  acc += dnb * s;
  o = offc[n]; e = o + cntc[n];
  s = 0.f;
  for (; o < e; ++o) { int src = listc[o]; s += dinvc[src] * bf2f(xwc[(size_t)src * HH + c]); }
  acc += dnc * s;
  if (RELU) acc = fmaxf(acc, 0.f);
  out[(size_t)n * HH + c] = f2bf(acc);
}

// ---------------- edge MLP v6: persistent blocks, W1^T fully LDS-resident ----------------
// Grid = 512 (2 blocks/CU); block stages ALL of W1^T (64KB, swizzled) ONCE, then
// grid-strides over edge tiles of 128. Next tile's A rows prefetched into the
// alternate register set during current tile's MFMA loop. No barriers in tile loop.
// PASS2=0: BN stats into st[rel].  PASS2=1: recompute, BN-apply, out = t_hat@W2 + b2.

#define LOAD_IDX(TT, S0, D0, S1, D1)                        \
  {                                                         \
    int base_ = (TT) * 128 + wid * 32;                      \
    int rr0_ = min(base_ + lr, EE - 1);                     \
    int rr1_ = min(base_ + 16 + lr, EE - 1);                \
    S0 = ei[rr0_]; D0 = ei[EE + rr0_];                      \
    S1 = ei[rr1_]; D1 = ei[EE + rr1_];                      \
  }

#define LOAD_A(S0, D0, S1, D1, A_)                                             \
  {                                                                            \
    _Pragma("unroll") for (int ks = 0; ks < 4; ++ks) {                         \
      A_[ks]      = *(const bf16x8*)(h2b + (size_t)(S0) * HH + ks * 32 + lg * 8); \
      A_[4 + ks]  = *(const bf16x8*)(h2b + (size_t)(D0) * HH + ks * 32 + lg * 8); \
      A_[8 + ks]  = *(const bf16x8*)(h2b + (size_t)(S1) * HH + ks * 32 + lg * 8); \
      A_[12 + ks] = *(const bf16x8*)(h2b + (size_t)(D1) * HH + ks * 32 + lg * 8); \
    }                                                                          \
  }

#define TILE_BODY(A_, TT)                                                       \
  {                                                                             \
    f32x4 acc[2][8];                                                            \
    _Pragma("unroll") for (int mf = 0; mf < 2; ++mf)                            \
      _Pragma("unroll") for (int nf = 0; nf < 8; ++nf)                          \
        acc[mf][nf] = (f32x4){0.f, 0.f, 0.f, 0.f};                              \
    _Pragma("unroll") for (int ks = 0; ks < 4; ++ks) {                          \
      _Pragma("unroll") for (int nf = 0; nf < 8; ++nf) {                        \
        int col = nf * 16 + lr;                                                 \
        int lb = (col * 512 + ks * 64 + lg * 16) ^ ((col & 7) << 4);            \
        bf16x8 b = *(const bf16x8*)((const char*)Bs + lb);                      \
        acc[0][nf] = __builtin_amdgcn_mfma_f32_16x16x32_bf16(A_[ks], b, acc[0][nf], 0, 0, 0);      \
        acc[1][nf] = __builtin_amdgcn_mfma_f32_16x16x32_bf16(A_[8 + ks], b, acc[1][nf], 0, 0, 0);  \
      }                                                                         \
    }                                                                           \
    _Pragma("unroll") for (int ks = 0; ks < 4; ++ks) {                          \
      _Pragma("unroll") for (int nf = 0; nf < 8; ++nf) {                        \
        int col = nf * 16 + lr;                                                 \
        int lb = (col * 512 + 256 + ks * 64 + lg * 16) ^ ((col & 7) << 4);      \
        bf16x8 b = *(const bf16x8*)((const char*)Bs + lb);                      \
        acc[0][nf] = __builtin_amdgcn_mfma_f32_16x16x32_bf16(A_[4 + ks], b, acc[0][nf], 0, 0, 0);  \
        acc[1][nf] = __builtin_amdgcn_mfma_f32_16x16x32_bf16(A_[12 + ks], b, acc[1][nf], 0, 0, 0); \
      }                                                                         \
    }                                                                           \
    int e0_ = (TT) * 128 + wid * 32;                                            \
    if (!PASS2) {                                                               \
      _Pragma("unroll") for (int nf = 0; nf < 8; ++nf) {                        \
        int col = nf * 16 + lr;                                                 \
        float b1c = b1[col];                                                    \
        float s = 0.f, q = 0.f;                                                 \
        _Pragma("unroll") for (int mf = 0; mf < 2; ++mf)                        \
          _Pragma("unroll") for (int j = 0; j < 4; ++j) {                       \
            int row = e0_ + mf * 16 + lg * 4 + j;                               \
            if (row < EE) {                                                     \
              float v = fmaxf(acc[mf][nf][j] + b1c, 0.f);                       \
              s += v; q += v * v;                                               \
            }                                                                   \
          }                                                                     \
        s += __shfl_xor(s, 16, 64); s += __shfl_xor(s, 32, 64);                 \
        q += __shfl_xor(q, 16, 64); q += __shfl_xor(q, 32, 64);                 \
        if (lg == 0) { atomicAdd(&redA[col], s); atomicAdd(&redB[col], q); }    \
      }                                                                         \
    } else {                                                                    \
      float p0[2][4], p1[2][4];                                                 \
      _Pragma("unroll") for (int mf = 0; mf < 2; ++mf)                          \
        _Pragma("unroll") for (int j = 0; j < 4; ++j) { p0[mf][j] = 0.f; p1[mf][j] = 0.f; } \
      _Pragma("unroll") for (int nf = 0; nf < 8; ++nf) {                        \
        int col = nf * 16 + lr;                                                 \
        float b1c = b1[col], sc = scale[col], sh = shift[col];                  \
        float w20 = W2[col * 2], w21 = W2[col * 2 + 1];                         \
        _Pragma("unroll") for (int mf = 0; mf < 2; ++mf)                        \
          _Pragma("unroll") for (int j = 0; j < 4; ++j) {                       \
            float v = fmaxf(acc[mf][nf][j] + b1c, 0.f) * sc + sh;               \
            p0[mf][j] += v * w20;                                               \
            p1[mf][j] += v * w21;                                               \
          }                                                                     \
      }                                                                         \
      _Pragma("unroll") for (int m = 8; m >= 1; m >>= 1) {                      \
        _Pragma("unroll") for (int mf = 0; mf < 2; ++mf)                        \
          _Pragma("unroll") for (int j = 0; j < 4; ++j) {                       \
            p0[mf][j] += __shfl_xor(p0[mf][j], m, 64);                          \
            p1[mf][j] += __shfl_xor(p1[mf][j], m, 64);                          \
          }                                                                     \
      }                                                                         \
      if (lr == 0) {                                                            \
        float b20 = b2[0], b21 = b2[1];                                         \
        _Pragma("unroll") for (int mf = 0; mf < 2; ++mf)                        \
          _Pragma("unroll") for (int j = 0; j < 4; ++j) {                       \
            int row = e0_ + mf * 16 + lg * 4 + j;                               \
            if (row < EE) {                                                     \
              o_[(size_t)row * 2 + 0] = p0[mf][j] + b20;                        \
              o_[(size_t)row * 2 + 1] = p1[mf][j] + b21;                        \
            }                                                                   \
          }                                                                     \
      }                                                                         \
    }                                                                           \
  }

template <int PASS2>
__global__ __launch_bounds__(256, 2) void k_edge_mlp6(
    const ushort* __restrict__ h2b,
    const int* __restrict__ ei0, const ushort* __restrict__ Wt0, const float* __restrict__ b1_0,
    const int* __restrict__ ei1, const ushort* __restrict__ Wt1, const float* __restrict__ b1_1,
    float* __restrict__ st,
    const float* __restrict__ W2_0, const float* __restrict__ b2_0,
    const float* __restrict__ W2_1, const float* __restrict__ b2_1,
    float* __restrict__ out, int nt) {
  const int rel = blockIdx.x >> 8;       // grid = 512
  const int blk = blockIdx.x & 255;
  const int* ei = rel ? ei1 : ei0;
  const ushort* W1t = rel ? Wt1 : Wt0;
  const float* b1 = rel ? b1_1 : b1_0;
  const float* scale = st + 4 * HH + rel * 2 * HH;
  const float* shift = scale + HH;
  const float* W2 = rel ? W2_1 : W2_0;
  const float* b2 = rel ? b2_1 : b2_0;
  float* o_ = out + (size_t)rel * 2 * EE;

  __shared__ ushort Bs[128 * 256];       // 64KB: full W1^T, swizzled
  __shared__ float redA[HH], redB[HH];

  const int t = threadIdx.x;
  const int l = t & 63, wid = t >> 6;
  const int lr = l & 15, lg = l >> 4;

  if (!PASS2) {
    if (t < HH) { redA[t] = 0.f; redB[t] = 0.f; }
  }

  // ---- stage full W1^T once: 4096 x 16B chunks, swizzled ----
#pragma unroll
  for (int i = 0; i < 16; ++i) {
    int c = i * 256 + t;
    int col = c >> 5, part = c & 31;
    int lb = (col * 512 + part * 16) ^ ((col & 7) << 4);
    *(bf16x8*)((char*)Bs + lb) = *(const bf16x8*)(W1t + col * 256 + part * 8);
  }

  // prologue: prefetch first tile into set X (overlaps staging drain)
  int tt = blk;
  int sX0 = 0, dX0 = 0, sX1 = 0, dX1 = 0, sY0 = 0, dY0 = 0, sY1 = 0, dY1 = 0;
  bf16x8 AX[16], AY[16];
  if (tt < nt) {
    LOAD_IDX(tt, sX0, dX0, sX1, dX1);
    LOAD_A(sX0, dX0, sX1, dX1, AX);
  }
  __syncthreads();

  // tile loop, 2-stage software pipeline (X computes while Y prefetches)
  for (; tt < nt; tt += 512) {
    {
      int tn = tt + 256;
      if (tn < nt) {
        LOAD_IDX(tn, sY0, dY0, sY1, dY1);
        LOAD_A(sY0, dY0, sY1, dY1, AY);
      }
      TILE_BODY(AX, tt);
    }
    {
      int tn = tt + 256;
      if (tn >= nt) break;
      int tnn = tn + 256;
      if (tnn < nt) {
        LOAD_IDX(tnn, sX0, dX0, sX1, dX1);
        LOAD_A(sX0, dX0, sX1, dX1, AX);
      }
      TILE_BODY(AY, tn);
    }
  }

  if (!PASS2) {
    float* gsum = st + rel * 2 * HH;
    float* gsq  = gsum + HH;
    __syncthreads();
    if (t < HH) {
      atomicAdd(&gsum[t], redA[t]);
      atomicAdd(&gsq[t], redB[t]);
    }
  }
}

// ---------------- edge types ----------------
__global__ void k_edge_types(float* __restrict__ out) {
  int i = blockIdx.x * 256 + threadIdx.x;
  if (i < 2 * EE) out[(size_t)2 * EE * 2 + i] = (i < EE) ? 0.0f : 1.0f;
}

extern "C" void kernel_launch(void* const* d_in, const int* in_sizes, int n_in,
                              void* d_out, int out_size, void* d_ws, size_t ws_size,
                              hipStream_t stream) {
  const float* x      = (const float*)d_in[0];
  const int*   bei    = (const int*)d_in[1];
  const int*   cei    = (const int*)d_in[2];
  const float* W_enc  = (const float*)d_in[3];
  const float* b_enc  = (const float*)d_in[4];
  const float* g_enc  = (const float*)d_in[5];
  const float* be_enc = (const float*)d_in[6];
  const float* W1b = (const float*)d_in[7];  const float* b1b = (const float*)d_in[8];
  const float* W1c = (const float*)d_in[9];  const float* b1c = (const float*)d_in[10];
  const float* W2b = (const float*)d_in[11]; const float* b2b = (const float*)d_in[12];
  const float* W2c = (const float*)d_in[13]; const float* b2c = (const float*)d_in[14];
  const float* Wbp1 = (const float*)d_in[15]; const float* bbp1 = (const float*)d_in[16];
  const float* gbp  = (const float*)d_in[17]; const float* bebp = (const float*)d_in[18];
  const float* Wbp2 = (const float*)d_in[19]; const float* bbp2 = (const float*)d_in[20];
  const float* Wcp1 = (const float*)d_in[21]; const float* bcp1 = (const float*)d_in[22];
  const float* gcp  = (const float*)d_in[23]; const float* becp = (const float*)d_in[24];
  const float* Wcp2 = (const float*)d_in[25]; const float* bcp2 = (const float*)d_in[26];
  float* out = (float*)d_out;

  // ---- workspace layout (~57 MB) ----
  ushort* hb   = (ushort*)d_ws;                 // h (bf16); later h2  [N*H]
  ushort* h1b  = hb + (size_t)NN * HH;          // h1 bf16
  ushort* xwb  = h1b + (size_t)NN * HH;         // per-relation x@W bf16
  ushort* xwc  = xwb + (size_t)NN * HH;
  ushort* Wt1b = xwc + (size_t)NN * HH;         // 128x128 transposed weights (bf16)
  ushort* Wt1c = Wt1b + 128 * 128;
  ushort* Wt2b = Wt1c + 128 * 128;
  ushort* Wt2c = Wt2b + 128 * 128;
  ushort* Wmb  = Wt2c + 128 * 128;              // MLP W1^T [128][256]
  ushort* Wmc  = Wmb + 256 * 128;
  float* dinv  = (float*)(Wmc + 256 * 128);     // dinvb[N], dinvc[N]
  float* dinvb = dinv, *dinvc = dinv + NN;
  float* st    = dinvc + NN;                    // [sum0,sq0,sum1,sq1,scale0,shift0,scale1,shift1]
  int* cnt  = (int*)(st + 8 * HH);              // cntb[N], cntc[N]
  int* cntb = cnt, *cntc = cnt + NN;
  int* offb = cntc + NN; int* offc = offb + NN;
  int* curb = offc + NN; int* curc = curb + NN;
  int* part = curc + NN;                        // scan partials [2*SCB]
  int* listb = part + 2 * SCB; int* listc = listb + EE;

  // ---- degrees + CSR (parallel scan) ----
  hipMemsetAsync(cnt, 0, sizeof(int) * 2 * NN, stream);
  hipMemsetAsync(st, 0, sizeof(float) * 2 * HH, stream);
  k_count<<<(2 * EE + 255) / 256, 256, 0, stream>>>(bei, cei, cntb, cntc);
  k_dinv<<<(2 * NN + 255) / 256, 256, 0, stream>>>(cnt, dinv);
  k_scan_part<<<2 * SCB, 256, 0, stream>>>(cnt, part);
  k_scan_base<<<1, 256, 0, stream>>>(part);
  k_scan_off<<<2 * SCB, 256, 0, stream>>>(cnt, part, offb, curb);
  k_fill<<<(2 * EE + 255) / 256, 256, 0, stream>>>(bei, cei, curb, listb, curc, listc);

  // ---- encoder + BN -> hb (bf16) ----
  k_encoder_bf<<<(NN + 63) / 64, 256, 0, stream>>>(x, W_enc, b_enc, hb, st, st + HH);
  k_bn_finalize<<<1, 128, 0, stream>>>(st, st + HH, g_enc, be_enc, st + 4 * HH, st + 5 * HH,
                                       1.0f / NN);
  k_bn_apply_bf<<<(NN * HH / 4 + 255) / 256, 256, 0, stream>>>(hb, st + 4 * HH, st + 5 * HH);

  // ---- weight transposes ----
  k_wt128_all<<<(4 * 16384 + 255) / 256, 256, 0, stream>>>(W1b, W1c, W2b, W2c,
                                                           Wt1b, Wt1c, Wt2b, Wt2c);
  k_wt256_all<<<(2 * 32768 + 255) / 256, 256, 0, stream>>>(Wbp1, Wcp1, Wmb, Wmc);

  int gblk = (NN + 63) / 64;
  int ablk = (NN + 1) / 2;
  // ---- GCN layer 1: h1 = relu(agg_b + agg_c) ----
  k_gemm_bf2<<<2 * gblk, 256, 0, stream>>>(hb, Wt1b, xwb, Wt1c, xwc);
  k_agg<1><<<ablk, 256, 0, stream>>>(xwb, xwc, dinvb, dinvc, offb, cntb, listb,
                                     offc, cntc, listc, b1b, b1c, h1b);
  // ---- GCN layer 2: h2 (into hb slot) ----
  k_gemm_bf2<<<2 * gblk, 256, 0, stream>>>(h1b, Wt2b, xwb, Wt2c, xwc);
  k_agg<0><<<ablk, 256, 0, stream>>>(xwb, xwc, dinvb, dinvc, offb, cntb, listb,
                                     offc, cntc, listc, b2b, b2c, hb);

  // ---- edge predictors (both relations per launch; persistent blocks) ----
  int nt = (EE + 127) / 128;  // 1954 tiles per relation
  hipMemsetAsync(st, 0, sizeof(float) * 4 * HH, stream);
  k_edge_mlp6<0><<<512, 256, 0, stream>>>(hb, bei, Wmb, bbp1, cei, Wmc, bcp1, st,
                                          nullptr, nullptr, nullptr, nullptr, nullptr, nt);
  k_bn_finalize2<<<1, 256, 0, stream>>>(st, gbp, bebp, gcp, becp, 1.0f / EE);
  k_edge_mlp6<1><<<512, 256, 0, stream>>>(hb, bei, Wmb, bbp1, cei, Wmc, bcp1, st,
                                          Wbp2, bbp2, Wcp2, bcp2, out, nt);

  k_edge_types<<<(2 * EE + 255) / 256, 256, 0, stream>>>(out);
}

// Round 8
// 613.055 us; speedup vs baseline: 1.4538x; 1.4538x over previous
//
#include <hip/hip_runtime.h>
#include <hip/hip_bf16.h>

#define NN 50000
#define EE 250000
#define HH 128
#define EPS_ 1e-5f
#define SCB 196  // scan segments per relation: ceil(NN/256)

typedef __attribute__((ext_vector_type(8))) short bf16x8;
typedef __attribute__((ext_vector_type(4))) float f32x4;

__device__ __forceinline__ float bf2f(ushort u) {
  union { unsigned int i; float f; } x; x.i = ((unsigned int)u) << 16; return x.f;
}
__device__ __forceinline__ ushort f2bf(float f) {
  union { float f; unsigned int i; } x; x.f = f;
  unsigned int r = (x.i + 0x7fffu + ((x.i >> 16) & 1u)) >> 16;  // RNE, finite inputs
  return (ushort)r;
}

// ---------------- degree / CSR build ----------------
__global__ void k_count(const int* __restrict__ bei, const int* __restrict__ cei,
                        int* __restrict__ cntb, int* __restrict__ cntc) {
  int i = blockIdx.x * blockDim.x + threadIdx.x;
  if (i < EE) atomicAdd(&cntb[bei[EE + i]], 1);
  else if (i < 2 * EE) atomicAdd(&cntc[cei[EE + (i - EE)]], 1);
}

__global__ void k_dinv(const int* __restrict__ cnt, float* __restrict__ dinv) {
  int i = blockIdx.x * blockDim.x + threadIdx.x;  // 2N: [cntb|cntc] -> [dinvb|dinvc]
  if (i < 2 * NN) dinv[i] = rsqrtf((float)cnt[i] + 1.0f);
}

// ---- parallel 2-level exclusive scan over cnt[2N] -> off[2N], cur[2N] ----
__global__ void k_scan_part(const int* __restrict__ cnt, int* __restrict__ part) {
  int rel = blockIdx.x / SCB, b = blockIdx.x % SCB;
  int n = b * 256 + threadIdx.x;
  int v = (n < NN) ? cnt[rel * NN + n] : 0;
#pragma unroll
  for (int m = 32; m >= 1; m >>= 1) v += __shfl_xor(v, m, 64);
  __shared__ int red[4];
  if ((threadIdx.x & 63) == 0) red[threadIdx.x >> 6] = v;
  __syncthreads();
  if (threadIdx.x == 0) part[rel * SCB + b] = red[0] + red[1] + red[2] + red[3];
}

__global__ void k_scan_base(int* __restrict__ part) {
  __shared__ int s[256];
  int t = threadIdx.x;
  for (int rel = 0; rel < 2; ++rel) {
    int v = (t < SCB) ? part[rel * SCB + t] : 0;
    s[t] = v;
    __syncthreads();
    for (int ofs = 1; ofs < 256; ofs <<= 1) {
      int x = (t >= ofs) ? s[t - ofs] : 0;
      __syncthreads();
      s[t] += x;
      __syncthreads();
    }
    if (t < SCB) part[rel * SCB + t] = s[t] - v;  // exclusive
    __syncthreads();
  }
}

__global__ void k_scan_off(const int* __restrict__ cnt, const int* __restrict__ part,
                           int* __restrict__ off, int* __restrict__ cur) {
  int rel = blockIdx.x / SCB, b = blockIdx.x % SCB;
  int t = threadIdx.x;
  int n = b * 256 + t;
  int v = (n < NN) ? cnt[rel * NN + n] : 0;
  __shared__ int s[256];
  s[t] = v;
  __syncthreads();
  for (int ofs = 1; ofs < 256; ofs <<= 1) {
    int x = (t >= ofs) ? s[t - ofs] : 0;
    __syncthreads();
    s[t] += x;
    __syncthreads();
  }
  if (n < NN) {
    int o = part[rel * SCB + b] + s[t] - v;
    off[rel * NN + n] = o;
    cur[rel * NN + n] = o;
  }
}

// fill CSR; also record per sorted position: src node, dst node, original edge id
__global__ void k_fill(const int* __restrict__ bei, const int* __restrict__ cei,
                       int* __restrict__ curb, int* __restrict__ listb,
                       int* __restrict__ dlistb, int* __restrict__ elistb,
                       int* __restrict__ curc, int* __restrict__ listc,
                       int* __restrict__ dlistc, int* __restrict__ elistc) {
  int i = blockIdx.x * blockDim.x + threadIdx.x;
  if (i < EE) {
    int dst = bei[EE + i];
    int p = atomicAdd(&curb[dst], 1);
    listb[p] = bei[i];
    dlistb[p] = dst;
    elistb[p] = i;
  } else if (i < 2 * EE) {
    int e = i - EE;
    int dst = cei[EE + e];
    int p = atomicAdd(&curc[dst], 1);
    listc[p] = cei[e];
    dlistc[p] = dst;
    elistc[p] = e;
  }
}

// ---------------- encoder: relu(x@W_enc+b) -> bf16, accumulate BN stats ----------------
__global__ void k_encoder_bf(const float* __restrict__ x, const float* __restrict__ W,
                             const float* __restrict__ b, ushort* __restrict__ hb,
                             float* __restrict__ sum, float* __restrict__ sumsq) {
  int t = threadIdx.x;
  int c = t & 127, r = t >> 7;
  int n0 = blockIdx.x * 64;
  float w0 = W[c], w1 = W[HH + c], w2 = W[2 * HH + c], bb = b[c];
  float ls = 0.f, lss = 0.f;
  for (int rr = r; rr < 64; rr += 2) {
    int n = n0 + rr;
    if (n < NN) {
      float v = fmaxf(x[n * 3] * w0 + x[n * 3 + 1] * w1 + x[n * 3 + 2] * w2 + bb, 0.f);
      ushort u = f2bf(v);
      hb[(size_t)n * HH + c] = u;
      float vr = bf2f(u);          // stats on the rounded value (self-consistent BN)
      ls += vr; lss += vr * vr;
    }
  }
  __shared__ float red[2][HH];
  red[r][c] = ls; __syncthreads();
  if (r == 0) atomicAdd(&sum[c], red[0][c] + red[1][c]);
  __syncthreads();
  red[r][c] = lss; __syncthreads();
  if (r == 0) atomicAdd(&sumsq[c], red[0][c] + red[1][c]);
}

__global__ void k_bn_finalize(const float* __restrict__ sum, const float* __restrict__ sumsq,
                              const float* __restrict__ g, const float* __restrict__ be,
                              float* __restrict__ scale, float* __restrict__ shift, float invn) {
  int c = threadIdx.x;
  float m = sum[c] * invn;
  float v = fmaxf(sumsq[c] * invn - m * m, 0.f);
  float s = g[c] * rsqrtf(v + EPS_);
  scale[c] = s;
  shift[c] = be[c] - m * s;
}

// merged 2-relation finalize; st layout: [sum0,sq0,sum1,sq1,scale0,shift0,scale1,shift1]
__global__ void k_bn_finalize2(float* __restrict__ st, const float* __restrict__ g0,
                               const float* __restrict__ be0, const float* __restrict__ g1,
                               const float* __restrict__ be1, float invn) {
  int t = threadIdx.x;  // 256
  int rel = t >> 7, c = t & 127;
  const float* sum = st + rel * 2 * HH;
  const float* sq  = sum + HH;
  float* scale = st + 4 * HH + rel * 2 * HH;
  float* shift = scale + HH;
  const float* g = rel ? g1 : g0;
  const float* be = rel ? be1 : be0;
  float m = sum[c] * invn;
  float v = fmaxf(sq[c] * invn - m * m, 0.f);
  float s = g[c] * rsqrtf(v + EPS_);
  scale[c] = s;
  shift[c] = be[c] - m * s;
}

__global__ void k_bn_apply_bf(ushort* __restrict__ hb, const float* __restrict__ scale,
                              const float* __restrict__ shift) {
  int i = blockIdx.x * 256 + threadIdx.x;  // i over N*H/4
  if (i * 4 < NN * HH) {
    int base = i * 4, c0 = base & 127;
    ushort4 u = *(ushort4*)&hb[base];
    u.x = f2bf(bf2f(u.x) * scale[c0] + shift[c0]);
    u.y = f2bf(bf2f(u.y) * scale[c0 + 1] + shift[c0 + 1]);
    u.z = f2bf(bf2f(u.z) * scale[c0 + 2] + shift[c0 + 2]);
    u.w = f2bf(bf2f(u.w) * scale[c0 + 3] + shift[c0 + 3]);
    *(ushort4*)&hb[base] = u;
  }
}

// ---------------- weight transposes to bf16 ----------------
__global__ void k_wt128_all(const float* __restrict__ s0, const float* __restrict__ s1,
                            const float* __restrict__ s2, const float* __restrict__ s3,
                            ushort* __restrict__ d0, ushort* __restrict__ d1,
                            ushort* __restrict__ d2, ushort* __restrict__ d3) {
  int i = blockIdx.x * 256 + threadIdx.x;
  if (i < 4 * 128 * 128) {
    int sel = i >> 14, loc = i & 16383;
    int k = loc >> 7, c = loc & 127;
    const float* s = sel == 0 ? s0 : sel == 1 ? s1 : sel == 2 ? s2 : s3;
    ushort* d = sel == 0 ? d0 : sel == 1 ? d1 : sel == 2 ? d2 : d3;
    d[c * 128 + k] = f2bf(s[loc]);
  }
}

__global__ void k_wt256_all(const float* __restrict__ s0, const float* __restrict__ s1,
                            ushort* __restrict__ d0, ushort* __restrict__ d1) {
  int i = blockIdx.x * 256 + threadIdx.x;
  if (i < 2 * 256 * 128) {
    int sel = i >> 15, loc = i & 32767;
    int k = loc >> 7, c = loc & 127;
    const float* s = sel ? s1 : s0;
    ushort* d = sel ? d1 : d0;
    d[c * 256 + k] = f2bf(s[loc]);
  }
}

// ---------------- bf16 GEMM pair: Y{0,1}[N,128] = X[N,128] @ W{0,1} ----------------
__global__ __launch_bounds__(256) void k_gemm_bf2(const ushort* __restrict__ X,
                                                  const ushort* __restrict__ Wt0,
                                                  ushort* __restrict__ Y0,
                                                  const ushort* __restrict__ Wt1,
                                                  ushort* __restrict__ Y1) {
  const int nb = gridDim.x >> 1;
  const int rel = blockIdx.x >= nb;
  const int blk = rel ? blockIdx.x - nb : blockIdx.x;
  const ushort* Wt = rel ? Wt1 : Wt0;
  ushort* Y = rel ? Y1 : Y0;
  const int t = threadIdx.x;
  const int l = t & 63, wid = t >> 6;
  const int wm = wid >> 1, wn = wid & 1;
  const int lr = l & 15, lg = l >> 4;
  const int n0 = blk * 64;
  f32x4 acc[2][4];
#pragma unroll
  for (int mf = 0; mf < 2; ++mf)
#pragma unroll
    for (int nf = 0; nf < 4; ++nf) acc[mf][nf] = (f32x4){0.f, 0.f, 0.f, 0.f};
  int r0 = n0 + wm * 32 + lr;
  int rA = min(r0, NN - 1), rB = min(r0 + 16, NN - 1);
  const ushort* xa = X + (size_t)rA * HH + lg * 8;
  const ushort* xb = X + (size_t)rB * HH + lg * 8;
#pragma unroll
  for (int ks = 0; ks < 4; ++ks) {
    bf16x8 a0 = *(const bf16x8*)(xa + ks * 32);
    bf16x8 a1 = *(const bf16x8*)(xb + ks * 32);
#pragma unroll
    for (int nf = 0; nf < 4; ++nf) {
      int col = wn * 64 + nf * 16 + lr;
      bf16x8 b = *(const bf16x8*)(Wt + col * 128 + ks * 32 + lg * 8);
      acc[0][nf] = __builtin_amdgcn_mfma_f32_16x16x32_bf16(a0, b, acc[0][nf], 0, 0, 0);
      acc[1][nf] = __builtin_amdgcn_mfma_f32_16x16x32_bf16(a1, b, acc[1][nf], 0, 0, 0);
    }
  }
#pragma unroll
  for (int mf = 0; mf < 2; ++mf)
#pragma unroll
    for (int nf = 0; nf < 4; ++nf) {
      int col = wn * 64 + nf * 16 + lr;
#pragma unroll
      for (int j = 0; j < 4; ++j) {
        int row = n0 + wm * 32 + mf * 16 + lg * 4 + j;
        if (row < NN) Y[(size_t)row * HH + col] = f2bf(acc[mf][nf][j]);
      }
    }
}

// ---------------- fused aggregation: bias+self+both relations (+relu) -> bf16 ----------------
template <int RELU>
__global__ void k_agg(const ushort* __restrict__ xwb, const ushort* __restrict__ xwc,
                      const float* __restrict__ dinvb, const float* __restrict__ dinvc,
                      const int* __restrict__ offb, const int* __restrict__ cntb,
                      const int* __restrict__ listb,
                      const int* __restrict__ offc, const int* __restrict__ cntc,
                      const int* __restrict__ listc,
                      const float* __restrict__ bb, const float* __restrict__ bc,
                      ushort* __restrict__ out) {
  int t = threadIdx.x;
  int n = blockIdx.x * 2 + (t >> 7);
  int c = t & 127;
  if (n >= NN) return;
  float dnb = dinvb[n], dnc = dinvc[n];
  float acc = bb[c] + bc[c] + dnb * dnb * bf2f(xwb[(size_t)n * HH + c])
                            + dnc * dnc * bf2f(xwc[(size_t)n * HH + c]);
  int o = offb[n], e = o + cntb[n];
  float s = 0.f;
  for (; o < e; ++o) { int src = listb[o]; s += dinvb[src] * bf2f(xwb[(size_t)src * HH + c]); }
  acc += dnb * s;
  o = offc[n]; e = o + cntc[n];
  s = 0.f;
  for (; o < e; ++o) { int src = listc[o]; s += dinvc[src] * bf2f(xwc[(size_t)src * HH + c]); }
  acc += dnc * s;
  if (RELU) acc = fmaxf(acc, 0.f);
  out[(size_t)n * HH + c] = f2bf(acc);
}

// ---------------- edge MLP v7: v5 structure + dst-sorted edge ordering ----------------
// Edges are processed in CSR (dst-sorted) position order: dst gathers become
// cache-local (avg degree ~5 => ~6 distinct dst rows per 32 positions); src stays
// random. Output rows scatter via eid[position]. B (W1^T) staged in LDS swizzled.
// PASS2=0: BN stats into st[rel].  PASS2=1: recompute, BN-apply, out = t_hat@W2 + b2.
template <int PASS2>
__global__ __launch_bounds__(256, 4) void k_edge_mlp7(
    const ushort* __restrict__ h2b,
    const int* __restrict__ sl0, const int* __restrict__ dl0, const int* __restrict__ el0,
    const ushort* __restrict__ Wt0, const float* __restrict__ b1_0,
    const int* __restrict__ sl1, const int* __restrict__ dl1, const int* __restrict__ el1,
    const ushort* __restrict__ Wt1, const float* __restrict__ b1_1,
    float* __restrict__ st,
    const float* __restrict__ W2_0, const float* __restrict__ b2_0,
    const float* __restrict__ W2_1, const float* __restrict__ b2_1,
    float* __restrict__ out) {
  const int nb = gridDim.x >> 1;
  const int rel = blockIdx.x >= nb;
  const int blk = rel ? blockIdx.x - nb : blockIdx.x;
  const int* sl = rel ? sl1 : sl0;
  const int* dl = rel ? dl1 : dl0;
  const int* el = rel ? el1 : el0;
  const ushort* W1t = rel ? Wt1 : Wt0;
  const float* b1 = rel ? b1_1 : b1_0;

  __shared__ ushort Bs[128 * 128];      // 32KB: one K-half of W1^T, swizzled
  __shared__ float redA[HH], redB[HH];

  const int t = threadIdx.x;
  const int l = t & 63, wid = t >> 6;
  const int lr = l & 15, lg = l >> 4;
  const int e0 = blk * 128 + wid * 32;  // this wave's 32 sorted positions

  // position indices + src-row A prefetch issued first (overlap with staging)
  int r0 = min(e0 + lr, EE - 1);
  int r1 = min(e0 + 16 + lr, EE - 1);
  int s0 = sl[r0], d0 = dl[r0];
  int s1 = sl[r1], d1 = dl[r1];

  bf16x8 a0[4], a1[4];
#pragma unroll
  for (int ks = 0; ks < 4; ++ks) {
    a0[ks] = *(const bf16x8*)(h2b + (size_t)s0 * HH + ks * 32 + lg * 8);
    a1[ks] = *(const bf16x8*)(h2b + (size_t)s1 * HH + ks * 32 + lg * 8);
  }

  if (!PASS2) {
    if (t < HH) { redA[t] = 0.f; redB[t] = 0.f; }
  }

  // ---- stage half 0: k 0..127 of every col (2048 x 16B chunks) ----
#pragma unroll
  for (int i = 0; i < 8; ++i) {
    int c = i * 256 + t;
    int col = c >> 4, part = c & 15;
    int lb = (col * 256 + part * 16) ^ ((col & 7) << 4);
    *(bf16x8*)((char*)Bs + lb) = *(const bf16x8*)(W1t + col * 256 + part * 8);
  }
  __syncthreads();

  f32x4 acc[2][8];
#pragma unroll
  for (int mf = 0; mf < 2; ++mf)
#pragma unroll
    for (int nf = 0; nf < 8; ++nf) acc[mf][nf] = (f32x4){0.f, 0.f, 0.f, 0.f};

  // ---- src half compute ----
#pragma unroll
  for (int ks = 0; ks < 4; ++ks) {
#pragma unroll
    for (int nf = 0; nf < 8; ++nf) {
      int col = nf * 16 + lr;
      int lb = (col * 256 + ks * 64 + lg * 16) ^ ((col & 7) << 4);
      bf16x8 b = *(const bf16x8*)((const char*)Bs + lb);
      acc[0][nf] = __builtin_amdgcn_mfma_f32_16x16x32_bf16(a0[ks], b, acc[0][nf], 0, 0, 0);
      acc[1][nf] = __builtin_amdgcn_mfma_f32_16x16x32_bf16(a1[ks], b, acc[1][nf], 0, 0, 0);
    }
  }

  // issue dst-row A loads now (hide under half-1 staging + barriers); dst is cache-local
#pragma unroll
  for (int ks = 0; ks < 4; ++ks) {
    a0[ks] = *(const bf16x8*)(h2b + (size_t)d0 * HH + ks * 32 + lg * 8);
    a1[ks] = *(const bf16x8*)(h2b + (size_t)d1 * HH + ks * 32 + lg * 8);
  }
  __syncthreads();   // all waves done reading half-0 Bs

  // ---- stage half 1: k 128..255 ----
#pragma unroll
  for (int i = 0; i < 8; ++i) {
    int c = i * 256 + t;
    int col = c >> 4, part = c & 15;
    int lb = (col * 256 + part * 16) ^ ((col & 7) << 4);
    *(bf16x8*)((char*)Bs + lb) = *(const bf16x8*)(W1t + col * 256 + 128 + part * 8);
  }
  __syncthreads();

  // ---- dst half compute ----
#pragma unroll
  for (int ks = 0; ks < 4; ++ks) {
#pragma unroll
    for (int nf = 0; nf < 8; ++nf) {
      int col = nf * 16 + lr;
      int lb = (col * 256 + ks * 64 + lg * 16) ^ ((col & 7) << 4);
      bf16x8 b = *(const bf16x8*)((const char*)Bs + lb);
      acc[0][nf] = __builtin_amdgcn_mfma_f32_16x16x32_bf16(a0[ks], b, acc[0][nf], 0, 0, 0);
      acc[1][nf] = __builtin_amdgcn_mfma_f32_16x16x32_bf16(a1[ks], b, acc[1][nf], 0, 0, 0);
    }
  }

  if (!PASS2) {
    float* gsum = st + rel * 2 * HH;
    float* gsq  = gsum + HH;
#pragma unroll
    for (int nf = 0; nf < 8; ++nf) {
      int col = nf * 16 + lr;
      float b1c = b1[col];
      float s = 0.f, q = 0.f;
#pragma unroll
      for (int mf = 0; mf < 2; ++mf)
#pragma unroll
        for (int j = 0; j < 4; ++j) {
          int row = e0 + mf * 16 + lg * 4 + j;   // sorted position; 0..EE-1 exactly once
          if (row < EE) {
            float v = fmaxf(acc[mf][nf][j] + b1c, 0.f);
            s += v; q += v * v;
          }
        }
      // reduce across the 4 lg-groups (lanes differing in bits 4,5)
      s += __shfl_xor(s, 16, 64); s += __shfl_xor(s, 32, 64);
      q += __shfl_xor(q, 16, 64); q += __shfl_xor(q, 32, 64);
      if (lg == 0) { atomicAdd(&redA[col], s); atomicAdd(&redB[col], q); }
    }
    __syncthreads();
    if (t < HH) {
      atomicAdd(&gsum[t], redA[t]);
      atomicAdd(&gsq[t], redB[t]);
    }
  } else {
    const float* scale = st + 4 * HH + rel * 2 * HH;
    const float* shift = scale + HH;
    const float* W2 = rel ? W2_1 : W2_0;
    const float* b2 = rel ? b2_1 : b2_0;
    float* o = out + (size_t)rel * 2 * EE;
    float p0[2][4], p1[2][4];
#pragma unroll
    for (int mf = 0; mf < 2; ++mf)
#pragma unroll
      for (int j = 0; j < 4; ++j) { p0[mf][j] = 0.f; p1[mf][j] = 0.f; }
#pragma unroll
    for (int nf = 0; nf < 8; ++nf) {
      int col = nf * 16 + lr;
      float b1c = b1[col], sc = scale[col], sh = shift[col];
      float w20 = W2[col * 2], w21 = W2[col * 2 + 1];
#pragma unroll
      for (int mf = 0; mf < 2; ++mf)
#pragma unroll
        for (int j = 0; j < 4; ++j) {
          float v = fmaxf(acc[mf][nf][j] + b1c, 0.f) * sc + sh;
          p0[mf][j] += v * w20;
          p1[mf][j] += v * w21;
        }
    }
    // reduce across the 16 lr lanes (bits 0..3)
#pragma unroll
    for (int m = 8; m >= 1; m >>= 1) {
#pragma unroll
      for (int mf = 0; mf < 2; ++mf)
#pragma unroll
        for (int j = 0; j < 4; ++j) {
          p0[mf][j] += __shfl_xor(p0[mf][j], m, 64);
          p1[mf][j] += __shfl_xor(p1[mf][j], m, 64);
        }
    }
    if (lr == 0) {
      float b20 = b2[0], b21 = b2[1];
#pragma unroll
      for (int mf = 0; mf < 2; ++mf)
#pragma unroll
        for (int j = 0; j < 4; ++j) {
          int row = e0 + mf * 16 + lg * 4 + j;   // sorted position
          if (row < EE) {
            int eid = el[row];                   // original edge index
            o[(size_t)eid * 2 + 0] = p0[mf][j] + b20;
            o[(size_t)eid * 2 + 1] = p1[mf][j] + b21;
          }
        }
    }
  }
}

// ---------------- edge types ----------------
__global__ void k_edge_types(float* __restrict__ out) {
  int i = blockIdx.x * 256 + threadIdx.x;
  if (i < 2 * EE) out[(size_t)2 * EE * 2 + i] = (i < EE) ? 0.0f : 1.0f;
}

extern "C" void kernel_launch(void* const* d_in, const int* in_sizes, int n_in,
                              void* d_out, int out_size, void* d_ws, size_t ws_size,
                              hipStream_t stream) {
  const float* x      = (const float*)d_in[0];
  const int*   bei    = (const int*)d_in[1];
  const int*   cei    = (const int*)d_in[2];
  const float* W_enc  = (const float*)d_in[3];
  const float* b_enc  = (const float*)d_in[4];
  const float* g_enc  = (const float*)d_in[5];
  const float* be_enc = (const float*)d_in[6];
  const float* W1b = (const float*)d_in[7];  const float* b1b = (const float*)d_in[8];
  const float* W1c = (const float*)d_in[9];  const float* b1c = (const float*)d_in[10];
  const float* W2b = (const float*)d_in[11]; const float* b2b = (const float*)d_in[12];
  const float* W2c = (const float*)d_in[13]; const float* b2c = (const float*)d_in[14];
  const float* Wbp1 = (const float*)d_in[15]; const float* bbp1 = (const float*)d_in[16];
  const float* gbp  = (const float*)d_in[17]; const float* bebp = (const float*)d_in[18];
  const float* Wbp2 = (const float*)d_in[19]; const float* bbp2 = (const float*)d_in[20];
  const float* Wcp1 = (const float*)d_in[21]; const float* bcp1 = (const float*)d_in[22];
  const float* gcp  = (const float*)d_in[23]; const float* becp = (const float*)d_in[24];
  const float* Wcp2 = (const float*)d_in[25]; const float* bcp2 = (const float*)d_in[26];
  float* out = (float*)d_out;

  // ---- workspace layout (~61 MB) ----
  ushort* hb   = (ushort*)d_ws;                 // h (bf16); later h2  [N*H]
  ushort* h1b  = hb + (size_t)NN * HH;          // h1 bf16
  ushort* xwb  = h1b + (size_t)NN * HH;         // per-relation x@W bf16
  ushort* xwc  = xwb + (size_t)NN * HH;
  ushort* Wt1b = xwc + (size_t)NN * HH;         // 128x128 transposed weights (bf16)
  ushort* Wt1c = Wt1b + 128 * 128;
  ushort* Wt2b = Wt1c + 128 * 128;
  ushort* Wt2c = Wt2b + 128 * 128;
  ushort* Wmb  = Wt2c + 128 * 128;              // MLP W1^T [128][256]
  ushort* Wmc  = Wmb + 256 * 128;
  float* dinv  = (float*)(Wmc + 256 * 128);     // dinvb[N], dinvc[N]
  float* dinvb = dinv, *dinvc = dinv + NN;
  float* st    = dinvc + NN;                    // [sum0,sq0,sum1,sq1,scale0,shift0,scale1,shift1]
  int* cnt  = (int*)(st + 8 * HH);              // cntb[N], cntc[N]
  int* cntb = cnt, *cntc = cnt + NN;
  int* offb = cntc + NN; int* offc = offb + NN;
  int* curb = offc + NN; int* curc = curb + NN;
  int* part = curc + NN;                        // scan partials [2*SCB]
  int* listb  = part + 2 * SCB;                 // src node per sorted position
  int* listc  = listb + EE;
  int* dlistb = listc + EE;                     // dst node per sorted position
  int* dlistc = dlistb + EE;
  int* elistb = dlistc + EE;                    // original edge id per sorted position
  int* elistc = elistb + EE;

  // ---- degrees + CSR (parallel scan) ----
  hipMemsetAsync(cnt, 0, sizeof(int) * 2 * NN, stream);
  hipMemsetAsync(st, 0, sizeof(float) * 2 * HH, stream);
  k_count<<<(2 * EE + 255) / 256, 256, 0, stream>>>(bei, cei, cntb, cntc);
  k_dinv<<<(2 * NN + 255) / 256, 256, 0, stream>>>(cnt, dinv);
  k_scan_part<<<2 * SCB, 256, 0, stream>>>(cnt, part);
  k_scan_base<<<1, 256, 0, stream>>>(part);
  k_scan_off<<<2 * SCB, 256, 0, stream>>>(cnt, part, offb, curb);
  k_fill<<<(2 * EE + 255) / 256, 256, 0, stream>>>(bei, cei, curb, listb, dlistb, elistb,
                                                   curc, listc, dlistc, elistc);

  // ---- encoder + BN -> hb (bf16) ----
  k_encoder_bf<<<(NN + 63) / 64, 256, 0, stream>>>(x, W_enc, b_enc, hb, st, st + HH);
  k_bn_finalize<<<1, 128, 0, stream>>>(st, st + HH, g_enc, be_enc, st + 4 * HH, st + 5 * HH,
                                       1.0f / NN);
  k_bn_apply_bf<<<(NN * HH / 4 + 255) / 256, 256, 0, stream>>>(hb, st + 4 * HH, st + 5 * HH);

  // ---- weight transposes ----
  k_wt128_all<<<(4 * 16384 + 255) / 256, 256, 0, stream>>>(W1b, W1c, W2b, W2c,
                                                           Wt1b, Wt1c, Wt2b, Wt2c);
  k_wt256_all<<<(2 * 32768 + 255) / 256, 256, 0, stream>>>(Wbp1, Wcp1, Wmb, Wmc);

  int gblk = (NN + 63) / 64;
  int ablk = (NN + 1) / 2;
  // ---- GCN layer 1: h1 = relu(agg_b + agg_c) ----
  k_gemm_bf2<<<2 * gblk, 256, 0, stream>>>(hb, Wt1b, xwb, Wt1c, xwc);
  k_agg<1><<<ablk, 256, 0, stream>>>(xwb, xwc, dinvb, dinvc, offb, cntb, listb,
                                     offc, cntc, listc, b1b, b1c, h1b);
  // ---- GCN layer 2: h2 (into hb slot) ----
  k_gemm_bf2<<<2 * gblk, 256, 0, stream>>>(h1b, Wt2b, xwb, Wt2c, xwc);
  k_agg<0><<<ablk, 256, 0, stream>>>(xwb, xwc, dinvb, dinvc, offb, cntb, listb,
                                     offc, cntc, listc, b2b, b2c, hb);

  // ---- edge predictors (both relations per launch; dst-sorted positions) ----
  int mblk = (EE + 127) / 128;
  hipMemsetAsync(st, 0, sizeof(float) * 4 * HH, stream);
  k_edge_mlp7<0><<<2 * mblk, 256, 0, stream>>>(hb, listb, dlistb, elistb, Wmb, bbp1,
                                               listc, dlistc, elistc, Wmc, bcp1, st,
                                               nullptr, nullptr, nullptr, nullptr, nullptr);
  k_bn_finalize2<<<1, 256, 0, stream>>>(st, gbp, bebp, gcp, becp, 1.0f / EE);
  k_edge_mlp7<1><<<2 * mblk, 256, 0, stream>>>(hb, listb, dlistb, elistb, Wmb, bbp1,
                                               listc, dlistc, elistc, Wmc, bcp1, st,
                                               Wbp2, bbp2, Wcp2, bcp2, out);

  k_edge_types<<<(2 * EE + 255) / 256, 256, 0, stream>>>(out);
}

// Round 9
// 540.624 us; speedup vs baseline: 1.6485x; 1.1340x over previous
//
#include <hip/hip_runtime.h>
#include <hip/hip_bf16.h>

#define NN 50000
#define EE 250000
#define HH 128
#define EPS_ 1e-5f
#define SCB 196  // scan segments per relation: ceil(NN/256)

typedef __attribute__((ext_vector_type(8))) short bf16x8;
typedef __attribute__((ext_vector_type(4))) float f32x4;

__device__ __forceinline__ float bf2f(ushort u) {
  union { unsigned int i; float f; } x; x.i = ((unsigned int)u) << 16; return x.f;
}
__device__ __forceinline__ ushort f2bf(float f) {
  union { float f; unsigned int i; } x; x.f = f;
  unsigned int r = (x.i + 0x7fffu + ((x.i >> 16) & 1u)) >> 16;  // RNE, finite inputs
  return (ushort)r;
}

// st float layout:
// 0:sum0 128:sq0 256:sum1 384:sq1 | 512:scale0 640:shift0 768:scale1 896:shift1
// 1024:W2p0[256] 1280:W2p1[256] 1536:b2p0[2] 1538:b2p1[2]

// ---------------- degree / CSR build ----------------
__global__ void k_count(const int* __restrict__ bei, const int* __restrict__ cei,
                        int* __restrict__ cntb, int* __restrict__ cntc) {
  int i = blockIdx.x * blockDim.x + threadIdx.x;
  if (i < EE) atomicAdd(&cntb[bei[EE + i]], 1);
  else if (i < 2 * EE) atomicAdd(&cntc[cei[EE + (i - EE)]], 1);
}

__global__ void k_dinv(const int* __restrict__ cnt, float* __restrict__ dinv) {
  int i = blockIdx.x * blockDim.x + threadIdx.x;  // 2N
  if (i < 2 * NN) dinv[i] = rsqrtf((float)cnt[i] + 1.0f);
}

__global__ void k_scan_part(const int* __restrict__ cnt, int* __restrict__ part) {
  int rel = blockIdx.x / SCB, b = blockIdx.x % SCB;
  int n = b * 256 + threadIdx.x;
  int v = (n < NN) ? cnt[rel * NN + n] : 0;
#pragma unroll
  for (int m = 32; m >= 1; m >>= 1) v += __shfl_xor(v, m, 64);
  __shared__ int red[4];
  if ((threadIdx.x & 63) == 0) red[threadIdx.x >> 6] = v;
  __syncthreads();
  if (threadIdx.x == 0) part[rel * SCB + b] = red[0] + red[1] + red[2] + red[3];
}

__global__ void k_scan_base(int* __restrict__ part) {
  __shared__ int s[256];
  int t = threadIdx.x;
  for (int rel = 0; rel < 2; ++rel) {
    int v = (t < SCB) ? part[rel * SCB + t] : 0;
    s[t] = v;
    __syncthreads();
    for (int ofs = 1; ofs < 256; ofs <<= 1) {
      int x = (t >= ofs) ? s[t - ofs] : 0;
      __syncthreads();
      s[t] += x;
      __syncthreads();
    }
    if (t < SCB) part[rel * SCB + t] = s[t] - v;  // exclusive
    __syncthreads();
  }
}

__global__ void k_scan_off(const int* __restrict__ cnt, const int* __restrict__ part,
                           int* __restrict__ off, int* __restrict__ cur) {
  int rel = blockIdx.x / SCB, b = blockIdx.x % SCB;
  int t = threadIdx.x;
  int n = b * 256 + t;
  int v = (n < NN) ? cnt[rel * NN + n] : 0;
  __shared__ int s[256];
  s[t] = v;
  __syncthreads();
  for (int ofs = 1; ofs < 256; ofs <<= 1) {
    int x = (t >= ofs) ? s[t - ofs] : 0;
    __syncthreads();
    s[t] += x;
    __syncthreads();
  }
  if (n < NN) {
    int o = part[rel * SCB + b] + s[t] - v;
    off[rel * NN + n] = o;
    cur[rel * NN + n] = o;
  }
}

__global__ void k_fill(const int* __restrict__ bei, const int* __restrict__ cei,
                       int* __restrict__ curb, int* __restrict__ listb,
                       int* __restrict__ dlistb, int* __restrict__ elistb,
                       int* __restrict__ curc, int* __restrict__ listc,
                       int* __restrict__ dlistc, int* __restrict__ elistc) {
  int i = blockIdx.x * blockDim.x + threadIdx.x;
  if (i < EE) {
    int dst = bei[EE + i];
    int p = atomicAdd(&curb[dst], 1);
    listb[p] = bei[i];
    dlistb[p] = dst;
    elistb[p] = i;
  } else if (i < 2 * EE) {
    int e = i - EE;
    int dst = cei[EE + e];
    int p = atomicAdd(&curc[dst], 1);
    listc[p] = cei[e];
    dlistc[p] = dst;
    elistc[p] = e;
  }
}

// ---------------- encoder: relu(x@W_enc+b) -> bf16 (pre-BN), accumulate BN stats ----------------
__global__ void k_encoder_bf(const float* __restrict__ x, const float* __restrict__ W,
                             const float* __restrict__ b, ushort* __restrict__ hb,
                             float* __restrict__ sum, float* __restrict__ sumsq) {
  int t = threadIdx.x;
  int c = t & 127, r = t >> 7;
  int n0 = blockIdx.x * 64;
  float w0 = W[c], w1 = W[HH + c], w2 = W[2 * HH + c], bb = b[c];
  float ls = 0.f, lss = 0.f;
  for (int rr = r; rr < 64; rr += 2) {
    int n = n0 + rr;
    if (n < NN) {
      float v = fmaxf(x[n * 3] * w0 + x[n * 3 + 1] * w1 + x[n * 3 + 2] * w2 + bb, 0.f);
      ushort u = f2bf(v);
      hb[(size_t)n * HH + c] = u;
      float vr = bf2f(u);
      ls += vr; lss += vr * vr;
    }
  }
  __shared__ float red[2][HH];
  red[r][c] = ls; __syncthreads();
  if (r == 0) atomicAdd(&sum[c], red[0][c] + red[1][c]);
  __syncthreads();
  red[r][c] = lss; __syncthreads();
  if (r == 0) atomicAdd(&sumsq[c], red[0][c] + red[1][c]);
}

__global__ void k_bn_finalize(const float* __restrict__ sum, const float* __restrict__ sumsq,
                              const float* __restrict__ g, const float* __restrict__ be,
                              float* __restrict__ scale, float* __restrict__ shift, float invn) {
  int c = threadIdx.x;
  float m = sum[c] * invn;
  float v = fmaxf(sumsq[c] * invn - m * m, 0.f);
  float s = g[c] * rsqrtf(v + EPS_);
  scale[c] = s;
  shift[c] = be[c] - m * s;
}

// 2-relation finalize + BN-folded W2 (W2p = scale*W2, b2p = b2 + shift@W2)
__global__ void k_bn_finalize3(float* __restrict__ st, const float* __restrict__ g0,
                               const float* __restrict__ be0, const float* __restrict__ g1,
                               const float* __restrict__ be1,
                               const float* __restrict__ W2_0, const float* __restrict__ b2_0,
                               const float* __restrict__ W2_1, const float* __restrict__ b2_1,
                               float invn) {
  int t = threadIdx.x;  // 256
  int rel = t >> 7, c = t & 127;
  const float* sum = st + rel * 2 * HH;
  const float* sq  = sum + HH;
  float* scale = st + 512 + rel * 256;
  float* shift = scale + HH;
  const float* g = rel ? g1 : g0;
  const float* be = rel ? be1 : be0;
  const float* W2 = rel ? W2_1 : W2_0;
  float m = sum[c] * invn;
  float v = fmaxf(sq[c] * invn - m * m, 0.f);
  float sc = g[c] * rsqrtf(v + EPS_);
  float sh = be[c] - m * sc;
  scale[c] = sc;
  shift[c] = sh;
  float w20 = W2[c * 2], w21 = W2[c * 2 + 1];
  st[1024 + rel * 256 + c * 2 + 0] = sc * w20;
  st[1024 + rel * 256 + c * 2 + 1] = sc * w21;
  __shared__ float red[2][HH][2];
  red[rel][c][0] = sh * w20;
  red[rel][c][1] = sh * w21;
  __syncthreads();
  if (c < 2) {
    float s = 0.f;
    for (int i = 0; i < HH; ++i) s += red[rel][i][c];
    st[1536 + rel * 2 + c] = (rel ? b2_1 : b2_0)[c] + s;
  }
}

// ---------------- weight transposes to bf16 (merged) ----------------
__global__ void k_wt_all(const float* __restrict__ s0, const float* __restrict__ s1,
                         const float* __restrict__ s2, const float* __restrict__ s3,
                         ushort* __restrict__ d0, ushort* __restrict__ d1,
                         ushort* __restrict__ d2, ushort* __restrict__ d3,
                         const float* __restrict__ m0, const float* __restrict__ m1,
                         ushort* __restrict__ e0, ushort* __restrict__ e1) {
  int i = blockIdx.x * 256 + threadIdx.x;
  if (i < 4 * 16384) {
    int sel = i >> 14, loc = i & 16383;
    int k = loc >> 7, c = loc & 127;
    const float* s = sel == 0 ? s0 : sel == 1 ? s1 : sel == 2 ? s2 : s3;
    ushort* d = sel == 0 ? d0 : sel == 1 ? d1 : sel == 2 ? d2 : d3;
    d[c * 128 + k] = f2bf(s[loc]);
  } else if (i < 4 * 16384 + 2 * 32768) {
    int j = i - 4 * 16384;
    int sel = j >> 15, loc = j & 32767;
    int k = loc >> 7, c = loc & 127;
    const float* s = sel ? m1 : m0;
    ushort* d = sel ? e1 : e0;
    d[c * 256 + k] = f2bf(s[loc]);
  }
}

// ---------------- bf16 GEMM pair (optional fused BN on A-read) ----------------
template <int APPLYBN>
__global__ __launch_bounds__(256) void k_gemm_bf2(const ushort* __restrict__ X,
                                                  const ushort* __restrict__ Wt0,
                                                  ushort* __restrict__ Y0,
                                                  const ushort* __restrict__ Wt1,
                                                  ushort* __restrict__ Y1,
                                                  const float* __restrict__ bnsc,
                                                  const float* __restrict__ bnsh) {
  const int nb = gridDim.x >> 1;
  const int rel = blockIdx.x >= nb;
  const int blk = rel ? blockIdx.x - nb : blockIdx.x;
  const ushort* Wt = rel ? Wt1 : Wt0;
  ushort* Y = rel ? Y1 : Y0;
  const int t = threadIdx.x;
  const int l = t & 63, wid = t >> 6;
  const int wm = wid >> 1, wn = wid & 1;
  const int lr = l & 15, lg = l >> 4;
  const int n0 = blk * 64;
  f32x4 acc[2][4];
#pragma unroll
  for (int mf = 0; mf < 2; ++mf)
#pragma unroll
    for (int nf = 0; nf < 4; ++nf) acc[mf][nf] = (f32x4){0.f, 0.f, 0.f, 0.f};
  int r0 = n0 + wm * 32 + lr;
  int rA = min(r0, NN - 1), rB = min(r0 + 16, NN - 1);
  const ushort* xa = X + (size_t)rA * HH + lg * 8;
  const ushort* xb = X + (size_t)rB * HH + lg * 8;
#pragma unroll
  for (int ks = 0; ks < 4; ++ks) {
    bf16x8 a0 = *(const bf16x8*)(xa + ks * 32);
    bf16x8 a1 = *(const bf16x8*)(xb + ks * 32);
    if (APPLYBN) {
      int k0 = ks * 32 + lg * 8;
#pragma unroll
      for (int i = 0; i < 8; ++i) {
        float sc = bnsc[k0 + i], sh = bnsh[k0 + i];
        a0[i] = (short)f2bf(bf2f((ushort)a0[i]) * sc + sh);
        a1[i] = (short)f2bf(bf2f((ushort)a1[i]) * sc + sh);
      }
    }
#pragma unroll
    for (int nf = 0; nf < 4; ++nf) {
      int col = wn * 64 + nf * 16 + lr;
      bf16x8 b = *(const bf16x8*)(Wt + col * 128 + ks * 32 + lg * 8);
      acc[0][nf] = __builtin_amdgcn_mfma_f32_16x16x32_bf16(a0, b, acc[0][nf], 0, 0, 0);
      acc[1][nf] = __builtin_amdgcn_mfma_f32_16x16x32_bf16(a1, b, acc[1][nf], 0, 0, 0);
    }
  }
#pragma unroll
  for (int mf = 0; mf < 2; ++mf)
#pragma unroll
    for (int nf = 0; nf < 4; ++nf) {
      int col = wn * 64 + nf * 16 + lr;
#pragma unroll
      for (int j = 0; j < 4; ++j) {
        int row = n0 + wm * 32 + mf * 16 + lg * 4 + j;
        if (row < NN) Y[(size_t)row * HH + col] = f2bf(acc[mf][nf][j]);
      }
    }
}

// ---------------- fused aggregation ----------------
template <int RELU>
__global__ void k_agg(const ushort* __restrict__ xwb, const ushort* __restrict__ xwc,
                      const float* __restrict__ dinvb, const float* __restrict__ dinvc,
                      const int* __restrict__ offb, const int* __restrict__ cntb,
                      const int* __restrict__ listb,
                      const int* __restrict__ offc, const int* __restrict__ cntc,
                      const int* __restrict__ listc,
                      const float* __restrict__ bb, const float* __restrict__ bc,
                      ushort* __restrict__ out) {
  int t = threadIdx.x;
  int n = blockIdx.x * 2 + (t >> 7);
  int c = t & 127;
  if (n >= NN) return;
  float dnb = dinvb[n], dnc = dinvc[n];
  float acc = bb[c] + bc[c] + dnb * dnb * bf2f(xwb[(size_t)n * HH + c])
                            + dnc * dnc * bf2f(xwc[(size_t)n * HH + c]);
  int o = offb[n], e = o + cntb[n];
  float s = 0.f;
  for (; o < e; ++o) { int src = listb[o]; s += dinvb[src] * bf2f(xwb[(size_t)src * HH + c]); }
  acc += dnb * s;
  o = offc[n]; e = o + cntc[n];
  s = 0.f;
  for (; o < e; ++o) { int src = listc[o]; s += dinvc[src] * bf2f(xwc[(size_t)src * HH + c]); }
  acc += dnc * s;
  if (RELU) acc = fmaxf(acc, 0.f);
  out[(size_t)n * HH + c] = f2bf(acc);
}

// ---------------- edge MLP v8 ----------------
// MODE 0: pass1, stats only (fallback).  MODE 1: pass1 + store t (bf16) to tbuf.
// MODE 2: pass2 recompute (fallback).  Dst-sorted positions, LDS-swizzled B, XCD-chunked grid.
template <int MODE>
__global__ __launch_bounds__(256, 4) void k_edge_mlp8(
    const ushort* __restrict__ h2b,
    const int* __restrict__ sl0, const int* __restrict__ dl0, const int* __restrict__ el0,
    const ushort* __restrict__ Wt0, const float* __restrict__ b1_0,
    const int* __restrict__ sl1, const int* __restrict__ dl1, const int* __restrict__ el1,
    const ushort* __restrict__ Wt1, const float* __restrict__ b1_1,
    float* __restrict__ st,
    const float* __restrict__ W2_0, const float* __restrict__ b2_0,
    const float* __restrict__ W2_1, const float* __restrict__ b2_1,
    float* __restrict__ out, ushort* __restrict__ tbuf) {
  // bijective XCD-chunked swizzle (m204): consecutive tiles -> same XCD
  const int nwg = gridDim.x;
  const int q = nwg >> 3, rr_ = nwg & 7;
  const int xcd = blockIdx.x & 7;
  const int base = (xcd < rr_) ? xcd * (q + 1) : rr_ * (q + 1) + (xcd - rr_) * q;
  const int wgid = base + (blockIdx.x >> 3);
  const int nb = nwg >> 1;
  const int rel = wgid >= nb;
  const int blk = rel ? wgid - nb : wgid;

  const int* sl = rel ? sl1 : sl0;
  const int* dl = rel ? dl1 : dl0;
  const int* el = rel ? el1 : el0;
  const ushort* W1t = rel ? Wt1 : Wt0;
  const float* b1 = rel ? b1_1 : b1_0;

  __shared__ ushort Bs[128 * 128];      // 32KB: one K-half of W1^T, swizzled
  __shared__ float redA[HH], redB[HH];

  const int t = threadIdx.x;
  const int l = t & 63, wid = t >> 6;
  const int lr = l & 15, lg = l >> 4;
  const int e0 = blk * 128 + wid * 32;  // this wave's 32 sorted positions

  int r0 = min(e0 + lr, EE - 1);
  int r1 = min(e0 + 16 + lr, EE - 1);
  int s0 = sl[r0], d0 = dl[r0];
  int s1 = sl[r1], d1 = dl[r1];

  bf16x8 a0[4], a1[4];
#pragma unroll
  for (int ks = 0; ks < 4; ++ks) {
    a0[ks] = *(const bf16x8*)(h2b + (size_t)s0 * HH + ks * 32 + lg * 8);
    a1[ks] = *(const bf16x8*)(h2b + (size_t)s1 * HH + ks * 32 + lg * 8);
  }

  if (MODE != 2) {
    if (t < HH) { redA[t] = 0.f; redB[t] = 0.f; }
  }

  // ---- stage half 0 ----
#pragma unroll
  for (int i = 0; i < 8; ++i) {
    int c = i * 256 + t;
    int col = c >> 4, part = c & 15;
    int lb = (col * 256 + part * 16) ^ ((col & 7) << 4);
    *(bf16x8*)((char*)Bs + lb) = *(const bf16x8*)(W1t + col * 256 + part * 8);
  }
  __syncthreads();

  f32x4 acc[2][8];
#pragma unroll
  for (int mf = 0; mf < 2; ++mf)
#pragma unroll
    for (int nf = 0; nf < 8; ++nf) acc[mf][nf] = (f32x4){0.f, 0.f, 0.f, 0.f};

#pragma unroll
  for (int ks = 0; ks < 4; ++ks) {
#pragma unroll
    for (int nf = 0; nf < 8; ++nf) {
      int col = nf * 16 + lr;
      int lb = (col * 256 + ks * 64 + lg * 16) ^ ((col & 7) << 4);
      bf16x8 b = *(const bf16x8*)((const char*)Bs + lb);
      acc[0][nf] = __builtin_amdgcn_mfma_f32_16x16x32_bf16(a0[ks], b, acc[0][nf], 0, 0, 0);
      acc[1][nf] = __builtin_amdgcn_mfma_f32_16x16x32_bf16(a1[ks], b, acc[1][nf], 0, 0, 0);
    }
  }

#pragma unroll
  for (int ks = 0; ks < 4; ++ks) {
    a0[ks] = *(const bf16x8*)(h2b + (size_t)d0 * HH + ks * 32 + lg * 8);
    a1[ks] = *(const bf16x8*)(h2b + (size_t)d1 * HH + ks * 32 + lg * 8);
  }
  __syncthreads();

  // ---- stage half 1 ----
#pragma unroll
  for (int i = 0; i < 8; ++i) {
    int c = i * 256 + t;
    int col = c >> 4, part = c & 15;
    int lb = (col * 256 + part * 16) ^ ((col & 7) << 4);
    *(bf16x8*)((char*)Bs + lb) = *(const bf16x8*)(W1t + col * 256 + 128 + part * 8);
  }
  __syncthreads();

#pragma unroll
  for (int ks = 0; ks < 4; ++ks) {
#pragma unroll
    for (int nf = 0; nf < 8; ++nf) {
      int col = nf * 16 + lr;
      int lb = (col * 256 + ks * 64 + lg * 16) ^ ((col & 7) << 4);
      bf16x8 b = *(const bf16x8*)((const char*)Bs + lb);
      acc[0][nf] = __builtin_amdgcn_mfma_f32_16x16x32_bf16(a0[ks], b, acc[0][nf], 0, 0, 0);
      acc[1][nf] = __builtin_amdgcn_mfma_f32_16x16x32_bf16(a1[ks], b, acc[1][nf], 0, 0, 0);
    }
  }

  if (MODE != 2) {
    float* gsum = st + rel * 2 * HH;
    float* gsq  = gsum + HH;
    ushort* tb = tbuf + (size_t)rel * EE * HH;
#pragma unroll
    for (int nf = 0; nf < 8; ++nf) {
      int col = nf * 16 + lr;
      float b1c = b1[col];
      float s = 0.f, q_ = 0.f;
#pragma unroll
      for (int mf = 0; mf < 2; ++mf)
#pragma unroll
        for (int j = 0; j < 4; ++j) {
          int row = e0 + mf * 16 + lg * 4 + j;
          if (row < EE) {
            float v = fmaxf(acc[mf][nf][j] + b1c, 0.f);
            if (MODE == 1) {
              ushort u = f2bf(v);
              tb[(size_t)row * HH + col] = u;
              v = bf2f(u);   // stats on the stored (rounded) value
            }
            s += v; q_ += v * v;
          }
        }
      s += __shfl_xor(s, 16, 64); s += __shfl_xor(s, 32, 64);
      q_ += __shfl_xor(q_, 16, 64); q_ += __shfl_xor(q_, 32, 64);
      if (lg == 0) { atomicAdd(&redA[col], s); atomicAdd(&redB[col], q_); }
    }
    __syncthreads();
    if (t < HH) {
      atomicAdd(&gsum[t], redA[t]);
      atomicAdd(&gsq[t], redB[t]);
    }
  } else {
    const float* scale = st + 512 + rel * 256;
    const float* shift = scale + HH;
    const float* W2 = rel ? W2_1 : W2_0;
    const float* b2 = rel ? b2_1 : b2_0;
    float* o = out + (size_t)rel * 2 * EE;
    float p0[2][4], p1[2][4];
#pragma unroll
    for (int mf = 0; mf < 2; ++mf)
#pragma unroll
      for (int j = 0; j < 4; ++j) { p0[mf][j] = 0.f; p1[mf][j] = 0.f; }
#pragma unroll
    for (int nf = 0; nf < 8; ++nf) {
      int col = nf * 16 + lr;
      float b1c = b1[col], sc = scale[col], sh = shift[col];
      float w20 = W2[col * 2], w21 = W2[col * 2 + 1];
#pragma unroll
      for (int mf = 0; mf < 2; ++mf)
#pragma unroll
        for (int j = 0; j < 4; ++j) {
          float v = fmaxf(acc[mf][nf][j] + b1c, 0.f) * sc + sh;
          p0[mf][j] += v * w20;
          p1[mf][j] += v * w21;
        }
    }
#pragma unroll
    for (int m = 8; m >= 1; m >>= 1) {
#pragma unroll
      for (int mf = 0; mf < 2; ++mf)
#pragma unroll
        for (int j = 0; j < 4; ++j) {
          p0[mf][j] += __shfl_xor(p0[mf][j], m, 64);
          p1[mf][j] += __shfl_xor(p1[mf][j], m, 64);
        }
    }
    if (lr == 0) {
      float b20 = b2[0], b21 = b2[1];
#pragma unroll
      for (int mf = 0; mf < 2; ++mf)
#pragma unroll
        for (int j = 0; j < 4; ++j) {
          int row = e0 + mf * 16 + lg * 4 + j;
          if (row < EE) {
            int eid = el[row];
            o[(size_t)eid * 2 + 0] = p0[mf][j] + b20;
            o[(size_t)eid * 2 + 1] = p1[mf][j] + b21;
          }
        }
    }
  }
}

// ---------------- streaming pass2: out = t @ W2p + b2p (BN folded) ----------------
__global__ __launch_bounds__(256) void k_outdot(const ushort* __restrict__ tbuf,
                                                const int* __restrict__ el0,
                                                const int* __restrict__ el1,
                                                const float* __restrict__ st,
                                                float* __restrict__ out) {
  __shared__ float w2s[2][256];
  __shared__ float b2s[4];
  int t = threadIdx.x;
  w2s[0][t] = st[1024 + t];
  if (t < 256) w2s[1][t] = st[1280 + t];
  if (t < 4) b2s[t] = st[1536 + t];
  __syncthreads();
  int l = t & 63, wid = t >> 6;
  int sub = l & 7;
  int row = blockIdx.x * 32 + wid * 8 + (l >> 3);   // global row in [0, 2*EE)
  int rel = row >= EE;
  int pos = row - (rel ? EE : 0);
  const ushort* trow = tbuf + (size_t)row * HH + sub * 16;
  bf16x8 u0 = *(const bf16x8*)trow;
  bf16x8 u1 = *(const bf16x8*)(trow + 8);
  const float* w = w2s[rel];
  float p0 = 0.f, p1 = 0.f;
#pragma unroll
  for (int i = 0; i < 8; ++i) {
    int c = sub * 16 + i;
    float f = bf2f((ushort)u0[i]);
    p0 += f * w[c * 2]; p1 += f * w[c * 2 + 1];
  }
#pragma unroll
  for (int i = 0; i < 8; ++i) {
    int c = sub * 16 + 8 + i;
    float f = bf2f((ushort)u1[i]);
    p0 += f * w[c * 2]; p1 += f * w[c * 2 + 1];
  }
#pragma unroll
  for (int m = 4; m >= 1; m >>= 1) {
    p0 += __shfl_xor(p0, m, 64);
    p1 += __shfl_xor(p1, m, 64);
  }
  if (sub == 0) {
    int eid = (rel ? el1 : el0)[pos];
    float* o = out + (size_t)rel * 2 * EE + (size_t)eid * 2;
    o[0] = p0 + b2s[rel * 2];
    o[1] = p1 + b2s[rel * 2 + 1];
  }
}

// ---------------- edge types ----------------
__global__ void k_edge_types(float* __restrict__ out) {
  int i = blockIdx.x * 256 + threadIdx.x;
  if (i < 2 * EE) out[(size_t)2 * EE * 2 + i] = (i < EE) ? 0.0f : 1.0f;
}

extern "C" void kernel_launch(void* const* d_in, const int* in_sizes, int n_in,
                              void* d_out, int out_size, void* d_ws, size_t ws_size,
                              hipStream_t stream) {
  const float* x      = (const float*)d_in[0];
  const int*   bei    = (const int*)d_in[1];
  const int*   cei    = (const int*)d_in[2];
  const float* W_enc  = (const float*)d_in[3];
  const float* b_enc  = (const float*)d_in[4];
  const float* g_enc  = (const float*)d_in[5];
  const float* be_enc = (const float*)d_in[6];
  const float* W1b = (const float*)d_in[7];  const float* b1b = (const float*)d_in[8];
  const float* W1c = (const float*)d_in[9];  const float* b1c = (const float*)d_in[10];
  const float* W2b = (const float*)d_in[11]; const float* b2b = (const float*)d_in[12];
  const float* W2c = (const float*)d_in[13]; const float* b2c = (const float*)d_in[14];
  const float* Wbp1 = (const float*)d_in[15]; const float* bbp1 = (const float*)d_in[16];
  const float* gbp  = (const float*)d_in[17]; const float* bebp = (const float*)d_in[18];
  const float* Wbp2 = (const float*)d_in[19]; const float* bbp2 = (const float*)d_in[20];
  const float* Wcp1 = (const float*)d_in[21]; const float* bcp1 = (const float*)d_in[22];
  const float* gcp  = (const float*)d_in[23]; const float* becp = (const float*)d_in[24];
  const float* Wcp2 = (const float*)d_in[25]; const float* bcp2 = (const float*)d_in[26];
  float* out = (float*)d_out;

  // ---- workspace layout ----
  ushort* hb   = (ushort*)d_ws;                 // h (bf16, pre-BN); later h2  [N*H]
  ushort* h1b  = hb + (size_t)NN * HH;
  ushort* xwb  = h1b + (size_t)NN * HH;
  ushort* xwc  = xwb + (size_t)NN * HH;
  ushort* Wt1b = xwc + (size_t)NN * HH;
  ushort* Wt1c = Wt1b + 128 * 128;
  ushort* Wt2b = Wt1c + 128 * 128;
  ushort* Wt2c = Wt2b + 128 * 128;
  ushort* Wmb  = Wt2c + 128 * 128;              // MLP W1^T [128][256]
  ushort* Wmc  = Wmb + 256 * 128;
  float* dinv  = (float*)(Wmc + 256 * 128);
  float* dinvb = dinv, *dinvc = dinv + NN;
  float* st    = dinvc + NN;                    // 2048 floats (see layout above)
  int* cnt  = (int*)(st + 2048);
  int* cntb = cnt, *cntc = cnt + NN;
  int* offb = cntc + NN; int* offc = offb + NN;
  int* curb = offc + NN; int* curc = curb + NN;
  int* part = curc + NN;
  int* listb  = part + 2 * SCB;
  int* listc  = listb + EE;
  int* dlistb = listc + EE;
  int* dlistc = dlistb + EE;
  int* elistb = dlistc + EE;
  int* elistc = elistb + EE;
  ushort* tbuf = (ushort*)(elistc + EE);        // [2*EE][HH] bf16 t storage (gated)
  size_t need = (size_t)((char*)tbuf - (char*)d_ws) + (size_t)2 * EE * HH * sizeof(ushort);
  int storet = (ws_size >= need) ? 1 : 0;

  // ---- degrees + CSR ----
  hipMemsetAsync(cnt, 0, sizeof(int) * 2 * NN, stream);
  hipMemsetAsync(st, 0, sizeof(float) * 2 * HH, stream);
  k_count<<<(2 * EE + 255) / 256, 256, 0, stream>>>(bei, cei, cntb, cntc);
  k_dinv<<<(2 * NN + 255) / 256, 256, 0, stream>>>(cnt, dinv);
  k_scan_part<<<2 * SCB, 256, 0, stream>>>(cnt, part);
  k_scan_base<<<1, 256, 0, stream>>>(part);
  k_scan_off<<<2 * SCB, 256, 0, stream>>>(cnt, part, offb, curb);
  k_fill<<<(2 * EE + 255) / 256, 256, 0, stream>>>(bei, cei, curb, listb, dlistb, elistb,
                                                   curc, listc, dlistc, elistc);

  // ---- encoder + BN (scale/shift only; apply fused into layer-1 GEMM) ----
  k_encoder_bf<<<(NN + 63) / 64, 256, 0, stream>>>(x, W_enc, b_enc, hb, st, st + HH);
  k_bn_finalize<<<1, 128, 0, stream>>>(st, st + HH, g_enc, be_enc, st + 512, st + 640, 1.0f / NN);

  // ---- weight transposes (merged) ----
  k_wt_all<<<(4 * 16384 + 2 * 32768 + 255) / 256, 256, 0, stream>>>(
      W1b, W1c, W2b, W2c, Wt1b, Wt1c, Wt2b, Wt2c, Wbp1, Wcp1, Wmb, Wmc);

  int gblk = (NN + 63) / 64;
  int ablk = (NN + 1) / 2;
  // ---- GCN layer 1 (BN applied on A-read, bit-identical to separate apply) ----
  k_gemm_bf2<1><<<2 * gblk, 256, 0, stream>>>(hb, Wt1b, xwb, Wt1c, xwc, st + 512, st + 640);
  k_agg<1><<<ablk, 256, 0, stream>>>(xwb, xwc, dinvb, dinvc, offb, cntb, listb,
                                     offc, cntc, listc, b1b, b1c, h1b);
  // ---- GCN layer 2 ----
  k_gemm_bf2<0><<<2 * gblk, 256, 0, stream>>>(h1b, Wt2b, xwb, Wt2c, xwc, nullptr, nullptr);
  k_agg<0><<<ablk, 256, 0, stream>>>(xwb, xwc, dinvb, dinvc, offb, cntb, listb,
                                     offc, cntc, listc, b2b, b2c, hb);

  // ---- edge predictors ----
  int mblk = (EE + 127) / 128;
  hipMemsetAsync(st, 0, sizeof(float) * 4 * HH, stream);
  if (storet) {
    k_edge_mlp8<1><<<2 * mblk, 256, 0, stream>>>(hb, listb, dlistb, elistb, Wmb, bbp1,
                                                 listc, dlistc, elistc, Wmc, bcp1, st,
                                                 Wbp2, bbp2, Wcp2, bcp2, out, tbuf);
    k_bn_finalize3<<<1, 256, 0, stream>>>(st, gbp, bebp, gcp, becp,
                                          Wbp2, bbp2, Wcp2, bcp2, 1.0f / EE);
    k_outdot<<<2 * EE / 32, 256, 0, stream>>>(tbuf, elistb, elistc, st, out);
  } else {
    k_edge_mlp8<0><<<2 * mblk, 256, 0, stream>>>(hb, listb, dlistb, elistb, Wmb, bbp1,
                                                 listc, dlistc, elistc, Wmc, bcp1, st,
                                                 Wbp2, bbp2, Wcp2, bcp2, out, tbuf);
    k_bn_finalize3<<<1, 256, 0, stream>>>(st, gbp, bebp, gcp, becp,
                                          Wbp2, bbp2, Wcp2, bcp2, 1.0f / EE);
    k_edge_mlp8<2><<<2 * mblk, 256, 0, stream>>>(hb, listb, dlistb, elistb, Wmb, bbp1,
                                                 listc, dlistc, elistc, Wmc, bcp1, st,
                                                 Wbp2, bbp2, Wcp2, bcp2, out, tbuf);
  }

  k_edge_types<<<(2 * EE + 255) / 256, 256, 0, stream>>>(out);
}